// Round 16
// baseline (127.610 us; speedup 1.0000x reference)
//
#include <hip/hip_runtime.h>

#define EPS 1e-5f

typedef unsigned short u16;
typedef __attribute__((ext_vector_type(8))) __bf16 bf16x8;
typedef __attribute__((ext_vector_type(16))) float f32x16;
typedef __attribute__((ext_vector_type(8))) unsigned short ushort8;

__device__ inline float bf2f(u16 h) {
  union { unsigned u; float f; } x; x.u = ((unsigned)h) << 16; return x.f;
}
__device__ inline u16 f2bf(float f) {
  union { float f; unsigned u; } x; x.f = f;
  unsigned r = x.u + 0x7fffu + ((x.u >> 16) & 1u);
  return (u16)(r >> 16);
}
__device__ inline float sigmoidf(float x) { return 1.0f / (1.0f + __expf(-x)); }

// ---------------- cast: 4 equal-size f32 -> bf16(u16) arrays ----------------
__global__ __launch_bounds__(256) void cast4_f32_bf16(
    const float* __restrict__ s0, const float* __restrict__ s1,
    const float* __restrict__ s2, const float* __restrict__ s3,
    u16* __restrict__ d0, u16* __restrict__ d1,
    u16* __restrict__ d2, u16* __restrict__ d3, int n)
{
  const float* s = (blockIdx.y == 0) ? s0 : (blockIdx.y == 1) ? s1 : (blockIdx.y == 2) ? s2 : s3;
  u16*         d = (blockIdx.y == 0) ? d0 : (blockIdx.y == 1) ? d1 : (blockIdx.y == 2) ? d2 : d3;
  int i = (blockIdx.x * 256 + threadIdx.x) * 8;
  if (i >= n) return;
  float4 a = *(const float4*)(s + i);
  float4 b = *(const float4*)(s + i + 4);
  ushort8 o;
  o[0] = f2bf(a.x); o[1] = f2bf(a.y); o[2] = f2bf(a.z); o[3] = f2bf(a.w);
  o[4] = f2bf(b.x); o[5] = f2bf(b.y); o[6] = f2bf(b.z); o[7] = f2bf(b.w);
  *(ushort8*)(d + i) = o;
}

// ---------------- GEMM: C[m][n] = sum_k A[m][k] * W[n][k] -------------------
// R16 = 32x32x16 MFMA (R14/R15 verified win) x high occupancy (R11 verified
// +6%): 256x128 tile, BK=32, 512 thr (8 waves 4Mx2N, wave-tile 64x64 = 2x2
// frags of 32x32 -> acc 64 regs), LDS 48 KiB dbuf -> 2 blocks/CU (4 waves/
// SIMD, independent barrier groups; VGPR ~116 total fits cap 128).
// Grid 1024 blocks (R7 precedent: no non-GEMM anomaly, unlike 2048-block).
// Swizzle (64B-row derivation): slot = k8 ^ ((row>>1)&3); bank tally: even/
// odd rows use banks 0-15/16-31, f balances slot-pairs 8/8 per parity ->
// exactly 8 accesses/bank = b128 floor, conflict-free. Staging source col
// (tid&3)^((tid>>3)&3) invariant across thread's 2 chunk rows (+128 = bit7).
// Min-sync 2-barrier loop (R9-verified), counted vmcnt(3).
#define MFMA32x32_ __builtin_amdgcn_mfma_f32_32x32x16_bf16
#define ASG __attribute__((address_space(1)))
#define ASL __attribute__((address_space(3)))

#define GLL(p, lds) __builtin_amdgcn_global_load_lds( \
    (const ASG void*)(p), (ASL void*)(lds), 16, 0, 0);

// stage one K-tile: A 256x32 (2 chunks/thread) + B 128x32 (1 chunk/thread)
#define STAGE(nx, kn) \
  GLL(gA_0 + (kn), &sA[nx][(      tid) * 8]) \
  GLL(gA_1 + (kn), &sA[nx][(512 + tid) * 8]) \
  GLL(gB_0 + (kn), &sB[nx][(      tid) * 8])

// fragment loads: row = base + (l&31), slot immediate per k-step
#define LDA(mi, sl) (*(const bf16x8*)&sa[(arow + (mi) * 32) * 32 + (sl)])
#define LDB(nj, sl) (*(const bf16x8*)&sb[(brow + (nj) * 32) * 32 + (sl)])

#define VMW(n) asm volatile("s_waitcnt vmcnt(" #n ")" ::: "memory");
#define BAR __builtin_amdgcn_s_barrier();

// 4 MFMA for one k-step: mi 0-1 x nj 0-1
#define MFMA4(aa0, aa1, bb0, bb1) \
  acc[0][0] = MFMA32x32_(aa0, bb0, acc[0][0], 0, 0, 0); \
  acc[0][1] = MFMA32x32_(aa0, bb1, acc[0][1], 0, 0, 0); \
  acc[1][0] = MFMA32x32_(aa1, bb0, acc[1][0], 0, 0, 0); \
  acc[1][1] = MFMA32x32_(aa1, bb1, acc[1][1], 0, 0, 0);

__global__ __launch_bounds__(512, 4) void gemm256x128_dual(
    const u16* __restrict__ A0, const u16* __restrict__ W0, u16* __restrict__ C0,
    const u16* __restrict__ A1, const u16* __restrict__ W1, u16* __restrict__ C1)
{
  constexpr int K = 1024, N = 4096, NT = 32;  // K-tiles of 32

  __shared__ __attribute__((aligned(16))) u16 sA[2][256 * 32];  // 2 x 16 KiB
  __shared__ __attribute__((aligned(16))) u16 sB[2][128 * 32];  // 2 x  8 KiB

  // T1: bijective XCD swizzle (1024 blocks % 8 XCDs == 0)
  const int b0_ = blockIdx.x;
  const int bid = (b0_ & 7) * 128 + (b0_ >> 3);

  const u16* A  = (bid < 512) ? A0 : A1;
  const u16* Wm = (bid < 512) ? W0 : W1;
  u16*       C  = (bid < 512) ? C0 : C1;
  const int b2 = bid & 511;
  const int bm = (b2 >> 5) << 8;   // 16 m-tiles of 256
  const int bn = (b2 & 31) << 7;   // 32 n-tiles of 128

  const int tid = threadIdx.x;
  const int l  = tid & 63;
  const int w  = tid >> 6;   // wave 0..7
  const int wr = w >> 1;     // 0..3 -> M offset wr*64
  const int wc = w & 1;      // 0..1 -> N offset wc*64

  // staging: chunk c -> row c>>2, slot c&3 (linear LDS); A chunks tid and
  // 512+tid (rows r, r+128); B chunk tid. Global source col pre-swizzled:
  // k8 = (tid&3) ^ ((row>>1)&3), row = tid>>2; invariant across +128 rows.
  const int srow = tid >> 2;                       // 0..127
  const int scol = ((tid & 3) ^ ((tid >> 3) & 3)) * 8;
  const u16* gA_0 = A  + (size_t)(bm + srow) * K + scol;
  const u16* gA_1 = gA_0 + (size_t)128 * K;
  const u16* gB_0 = Wm + (size_t)(bn + srow) * K + scol;

  // fragment reads: row = base + (l&31); k-step s, granule g = l>>5:
  // slot = (2s + g) ^ ((row>>1)&3); (row>>1)&3 = ((l&31)>>1)&3 lane-only
  const int arow = wr * 64 + (l & 31);
  const int brow = wc * 64 + (l & 31);
  const int g  = l >> 5;
  const int xs = (l >> 1) & 3;   // ((l&31)>>1)&3 == (l>>1)&3 for l&31
  const int sl0 = ((0 + g) ^ xs) * 8;  // k-step 0
  const int sl1 = ((2 + g) ^ xs) * 8;  // k-step 1

  f32x16 acc[2][2];
#pragma unroll
  for (int i = 0; i < 2; ++i)
#pragma unroll
    for (int j = 0; j < 2; ++j)
#pragma unroll
      for (int r = 0; r < 16; ++r) acc[i][j][r] = 0.f;

  // prologue: stage K-tile 0 into buffer 0 (3 loads in flight, no drain)
  STAGE(0, 0)

  for (int t = 0; t < NT; ++t) {
    const int cur = t & 1, nxt = cur ^ 1;
    const u16* sa = sA[cur];
    const u16* sb = sB[cur];

    // stage t+1 (safe: BAR_A(t-1) retired all reads of buf[nxt]);
    // VMW before BAR_B makes tile t's arrival collective.
    if (t < NT - 1) {
      STAGE(nxt, (t + 1) * 32)
      VMW(3)
    } else {
      VMW(0)
    }
    BAR  // BAR_B

    bf16x8 a0e, a1e, a0o, a1o, b0e, b1e, b0o, b1o;
    b0e = LDB(0, sl0); b1e = LDB(1, sl0);
    b0o = LDB(0, sl1); b1o = LDB(1, sl1);
    a0e = LDA(0, sl0); a1e = LDA(1, sl0);
    a0o = LDA(0, sl1); a1o = LDA(1, sl1);
    MFMA4(a0e, a1e, b0e, b1e)
    MFMA4(a0o, a1o, b0o, b1o)

    BAR  // BAR_A: all waves' reads of buf[cur] retired (lgkm before MFMA)
  }

  // C write (m74/m101 layout): col = lane&31,
  // row = (reg&3) + 8*(reg>>2) + 4*(lane>>5)
  const int ccol = bn + wc * 64 + (l & 31);
  const int crow = bm + wr * 64 + 4 * (l >> 5);
#pragma unroll
  for (int mi = 0; mi < 2; ++mi) {
#pragma unroll
    for (int nj = 0; nj < 2; ++nj) {
      int col = ccol + nj * 32;
#pragma unroll
      for (int r = 0; r < 16; ++r) {
        int row = crow + mi * 32 + (r & 3) + 8 * (r >> 2);
        C[(size_t)row * N + col] = f2bf(acc[mi][nj][r]);
      }
    }
  }
}

// ---------------- fused LN(ig) + LN(hg) + gates + cell-LN + outputs ----------
__global__ __launch_bounds__(256) void lstm_epilogue(
    const u16* __restrict__ ig, const u16* __restrict__ hg,
    const float* __restrict__ cx,
    const float* __restrict__ gi, const float* __restrict__ bi,
    const float* __restrict__ gh, const float* __restrict__ bh,
    const float* __restrict__ gc, const float* __restrict__ bc,
    float* __restrict__ out)
{
  const int b = blockIdx.x;
  const int t = threadIdx.x;
  const u16* igr = ig + (size_t)b * 4096;
  const u16* hgr = hg + (size_t)b * 4096;

  __shared__ float redbuf[16];

  float iv[16], hv[16];
  float s_i = 0.f, q_i = 0.f, s_h = 0.f, q_h = 0.f;
#pragma unroll
  for (int i = 0; i < 16; ++i) {
    float a = bf2f(igr[t + 256 * i]);
    float c = bf2f(hgr[t + 256 * i]);
    iv[i] = a; hv[i] = c;
    s_i += a; q_i += a * a; s_h += c; q_h += c * c;
  }
#pragma unroll
  for (int off = 32; off > 0; off >>= 1) {
    s_i += __shfl_xor(s_i, off);
    q_i += __shfl_xor(q_i, off);
    s_h += __shfl_xor(s_h, off);
    q_h += __shfl_xor(q_h, off);
  }
  {
    int wv = t >> 6;
    if ((t & 63) == 0) {
      redbuf[wv] = s_i; redbuf[wv + 4] = q_i;
      redbuf[wv + 8] = s_h; redbuf[wv + 12] = q_h;
    }
    __syncthreads();
    s_i = redbuf[0] + redbuf[1] + redbuf[2] + redbuf[3];
    q_i = redbuf[4] + redbuf[5] + redbuf[6] + redbuf[7];
    s_h = redbuf[8] + redbuf[9] + redbuf[10] + redbuf[11];
    q_h = redbuf[12] + redbuf[13] + redbuf[14] + redbuf[15];
    __syncthreads();
  }
  const float inv4096 = 1.0f / 4096.0f;
  float mu_i = s_i * inv4096;
  float rs_i = rsqrtf(q_i * inv4096 - mu_i * mu_i + EPS);
  float mu_h = s_h * inv4096;
  float rs_h = rsqrtf(q_h * inv4096 - mu_h * mu_h + EPS);

  float c_pre[4], og[4];
  float s_c = 0.f, q_c = 0.f;
#pragma unroll
  for (int i = 0; i < 4; ++i) {
    int h = t + 256 * i;
    float g_in = ((iv[i]      - mu_i) * rs_i * gi[h]        + bi[h]) +
                 ((hv[i]      - mu_h) * rs_h * gh[h]        + bh[h]);
    float g_fg = ((iv[i + 4]  - mu_i) * rs_i * gi[h + 1024] + bi[h + 1024]) +
                 ((hv[i + 4]  - mu_h) * rs_h * gh[h + 1024] + bh[h + 1024]);
    float g_cl = ((iv[i + 8]  - mu_i) * rs_i * gi[h + 2048] + bi[h + 2048]) +
                 ((hv[i + 8]  - mu_h) * rs_h * gh[h + 2048] + bh[h + 2048]);
    float g_og = ((iv[i + 12] - mu_i) * rs_i * gi[h + 3072] + bi[h + 3072]) +
                 ((hv[i + 12] - mu_h) * rs_h * gh[h + 3072] + bh[h + 3072]);
    float in_s = sigmoidf(g_in);
    float fg_s = sigmoidf(g_fg);
    float cl_t = tanhf(g_cl);
    og[i] = sigmoidf(g_og);
    c_pre[i] = fg_s * cx[(size_t)b * 1024 + h] + in_s * cl_t;
    s_c += c_pre[i]; q_c += c_pre[i] * c_pre[i];
  }
#pragma unroll
  for (int off = 32; off > 0; off >>= 1) {
    s_c += __shfl_xor(s_c, off);
    q_c += __shfl_xor(q_c, off);
  }
  {
    int wv = t >> 6;
    if ((t & 63) == 0) { redbuf[wv] = s_c; redbuf[wv + 4] = q_c; }
    __syncthreads();
    s_c = redbuf[0] + redbuf[1] + redbuf[2] + redbuf[3];
    q_c = redbuf[4] + redbuf[5] + redbuf[6] + redbuf[7];
  }
  const float inv1024 = 1.0f / 1024.0f;
  float mu_c = s_c * inv1024;
  float rs_c = rsqrtf(q_c * inv1024 - mu_c * mu_c + EPS);

  const size_t BH = (size_t)4096 * 1024;
#pragma unroll
  for (int i = 0; i < 4; ++i) {
    int h = t + 256 * i;
    float cy = (c_pre[i] - mu_c) * rs_c * gc[h] + bc[h];
    float hy = og[i] * tanhf(cy);
    size_t o = (size_t)b * 1024 + h;
    out[o] = hy;
    out[BH + o] = hy;
    out[2 * BH + o] = cy;
  }
}

extern "C" void kernel_launch(void* const* d_in, const int* in_sizes, int n_in,
                              void* d_out, int out_size, void* d_ws, size_t ws_size,
                              hipStream_t stream) {
  const float* input = (const float*)d_in[0];
  const float* hx    = (const float*)d_in[1];
  const float* cx    = (const float*)d_in[2];
  const float* wih   = (const float*)d_in[3];
  const float* whh   = (const float*)d_in[4];
  const float* gi    = (const float*)d_in[5];
  const float* bi    = (const float*)d_in[6];
  const float* gh    = (const float*)d_in[7];
  const float* bh    = (const float*)d_in[8];
  const float* gc    = (const float*)d_in[9];
  const float* bc    = (const float*)d_in[10];
  float* out = (float*)d_out;

  char* wsp = (char*)d_ws;
  u16* a_bf  = (u16*)(wsp);
  u16* h_bf  = (u16*)(wsp + ((size_t)8  << 20));
  u16* wi_bf = (u16*)(wsp + ((size_t)16 << 20));
  u16* wh_bf = (u16*)(wsp + ((size_t)24 << 20));
  u16* ig_bf = (u16*)(wsp + ((size_t)32 << 20));
  u16* hg_bf = (u16*)(wsp + ((size_t)64 << 20));

  const int nper = 4096 * 1024;
  dim3 cgrid(nper / 8 / 256, 4);
  cast4_f32_bf16<<<cgrid, 256, 0, stream>>>(input, hx, wih, whh,
                                            a_bf, h_bf, wi_bf, wh_bf, nper);

  gemm256x128_dual<<<1024, 512, 0, stream>>>(a_bf, wi_bf, ig_bf,
                                             h_bf, wh_bf, hg_bf);

  lstm_epilogue<<<4096, 256, 0, stream>>>(ig_bf, hg_bf, cx,
                                          gi, bi, gh, bh, gc, bc, out);
}

// Round 17
// 119.287 us; speedup vs baseline: 1.0698x; 1.0698x over previous
//
#include <hip/hip_runtime.h>

#define EPS 1e-5f

typedef unsigned short u16;
typedef __attribute__((ext_vector_type(8))) __bf16 bf16x8;
typedef __attribute__((ext_vector_type(16))) float f32x16;
typedef __attribute__((ext_vector_type(8))) unsigned short ushort8;

__device__ inline float bf2f(u16 h) {
  union { unsigned u; float f; } x; x.u = ((unsigned)h) << 16; return x.f;
}
__device__ inline u16 f2bf(float f) {
  union { float f; unsigned u; } x; x.f = f;
  unsigned r = x.u + 0x7fffu + ((x.u >> 16) & 1u);
  return (u16)(r >> 16);
}
__device__ inline float sigmoidf(float x) { return 1.0f / (1.0f + __expf(-x)); }

// ---------------- cast: 4 equal-size f32 -> bf16(u16) arrays ----------------
__global__ __launch_bounds__(256) void cast4_f32_bf16(
    const float* __restrict__ s0, const float* __restrict__ s1,
    const float* __restrict__ s2, const float* __restrict__ s3,
    u16* __restrict__ d0, u16* __restrict__ d1,
    u16* __restrict__ d2, u16* __restrict__ d3, int n)
{
  const float* s = (blockIdx.y == 0) ? s0 : (blockIdx.y == 1) ? s1 : (blockIdx.y == 2) ? s2 : s3;
  u16*         d = (blockIdx.y == 0) ? d0 : (blockIdx.y == 1) ? d1 : (blockIdx.y == 2) ? d2 : d3;
  int i = (blockIdx.x * 256 + threadIdx.x) * 8;
  if (i >= n) return;
  float4 a = *(const float4*)(s + i);
  float4 b = *(const float4*)(s + i + 4);
  ushort8 o;
  o[0] = f2bf(a.x); o[1] = f2bf(a.y); o[2] = f2bf(a.z); o[3] = f2bf(a.w);
  o[4] = f2bf(b.x); o[5] = f2bf(b.y); o[6] = f2bf(b.z); o[7] = f2bf(b.w);
  *(ushort8*)(d + i) = o;
}

// ---------------- GEMM: C[m][n] = sum_k A[m][k] * W[n][k] -------------------
// FINAL (champion, R15: total 119.46 us, GEMM 86.5 us = ~777 TF, 0 bank
// conflicts, absmax 0.03125). 32x32x16 MFMA on the min-sync skeleton:
// 256x256 tile, BK=64, 512 thr (8 waves 2Mx4N, wave-tile 128x64 = 4x2 frags),
// 128 KiB LDS dbuf, 2 barriers/tile, counted vmcnt(8), swizzle
// slot = k8 ^ (row&7) ^ ((row>>3)&3) (verified 0 conflicts), XCD swizzle,
// pointer-advance staging (gload_lds offset-imm corrupts LDS-DMA, R6).
// Session ledger (R0-R16): merged dual GEMM +38us; counted vmcnt +9;
// min-sync +1; 32x32 shape +3.4; swizzle fix +1.1. Refuted/null: 8-phase
// m201 port (m232-OPEN confirmed), 3-buffer single-barrier, 2-blocks/CU at
// this tile (reg-capped), setprio/XCD-swz deltas, BK=32 swizzles (no valid
// bank model for 64B rows; 8.4M conflicts). fp8 excluded by accuracy
// (projected absmax ~0.2-0.3 > 0.142). Epilogue at HBM ceiling (6.4 TB/s).
#define MFMA32x32_ __builtin_amdgcn_mfma_f32_32x32x16_bf16
#define ASG __attribute__((address_space(1)))
#define ASL __attribute__((address_space(3)))

#define GLL(p, lds) __builtin_amdgcn_global_load_lds( \
    (const ASG void*)(p), (ASL void*)(lds), 16, 0, 0);

#define STAGE_A(nx, kn) \
  GLL(gA_0 + (kn), &sA[nx][((w << 6)       ) * 8]) \
  GLL(gA_1 + (kn), &sA[nx][((w << 6) +  512) * 8]) \
  GLL(gA_2 + (kn), &sA[nx][((w << 6) + 1024) * 8]) \
  GLL(gA_3 + (kn), &sA[nx][((w << 6) + 1536) * 8])
#define STAGE_B(nx, kn) \
  GLL(gB_0 + (kn), &sB[nx][((w << 6)       ) * 8]) \
  GLL(gB_1 + (kn), &sB[nx][((w << 6) +  512) * 8]) \
  GLL(gB_2 + (kn), &sB[nx][((w << 6) + 1024) * 8]) \
  GLL(gB_3 + (kn), &sB[nx][((w << 6) + 1536) * 8])

// fragment loads: row = base + (l&31), slot immediate per k-step s
#define LDA(mi, sl) (*(const bf16x8*)&sa[(arow + (mi) * 32) * 64 + (sl)])
#define LDB(nj, sl) (*(const bf16x8*)&sb[(brow + (nj) * 32) * 64 + (sl)])

#define VMW(n) asm volatile("s_waitcnt vmcnt(" #n ")" ::: "memory");
#define BAR __builtin_amdgcn_s_barrier();

// 8 MFMA for one k-step: mi 0-3 x nj 0-1 (frags aa0..aa3, bb0..bb1)
#define MFMA8(aa0, aa1, aa2, aa3, bb0, bb1) \
  acc[0][0] = MFMA32x32_(aa0, bb0, acc[0][0], 0, 0, 0); \
  acc[0][1] = MFMA32x32_(aa0, bb1, acc[0][1], 0, 0, 0); \
  acc[1][0] = MFMA32x32_(aa1, bb0, acc[1][0], 0, 0, 0); \
  acc[1][1] = MFMA32x32_(aa1, bb1, acc[1][1], 0, 0, 0); \
  acc[2][0] = MFMA32x32_(aa2, bb0, acc[2][0], 0, 0, 0); \
  acc[2][1] = MFMA32x32_(aa2, bb1, acc[2][1], 0, 0, 0); \
  acc[3][0] = MFMA32x32_(aa3, bb0, acc[3][0], 0, 0, 0); \
  acc[3][1] = MFMA32x32_(aa3, bb1, acc[3][1], 0, 0, 0);

// read 12 frags for k-steps s=2p, 2p+1 (4A+2B each)
#define RD12(slE, slO) \
  b0e = LDB(0, slE); b1e = LDB(1, slE); b0o = LDB(0, slO); b1o = LDB(1, slO); \
  a0e = LDA(0, slE); a1e = LDA(1, slE); a2e = LDA(2, slE); a3e = LDA(3, slE); \
  a0o = LDA(0, slO); a1o = LDA(1, slO); a2o = LDA(2, slO); a3o = LDA(3, slO);

__global__ __launch_bounds__(512, 2) void gemm256_dual(
    const u16* __restrict__ A0, const u16* __restrict__ W0, u16* __restrict__ C0,
    const u16* __restrict__ A1, const u16* __restrict__ W1, u16* __restrict__ C1)
{
  constexpr int K = 1024, N = 4096, NT = 16;  // K-tiles of 64

  __shared__ __attribute__((aligned(16))) u16 sA[2][256 * 64];  // 2 x 32 KiB
  __shared__ __attribute__((aligned(16))) u16 sB[2][256 * 64];  // 2 x 32 KiB

  // T1: bijective XCD swizzle (512 blocks % 8 XCDs == 0)
  const int b0_ = blockIdx.x;
  const int bid = (b0_ & 7) * 64 + (b0_ >> 3);

  const u16* A  = (bid < 256) ? A0 : A1;
  const u16* Wm = (bid < 256) ? W0 : W1;
  u16*       C  = (bid < 256) ? C0 : C1;
  const int b2 = bid & 255;
  const int bm = (b2 >> 4) << 8;
  const int bn = (b2 & 15) << 8;

  const int tid = threadIdx.x;
  const int l  = tid & 63;
  const int w  = tid >> 6;   // wave 0..7
  const int wr = w >> 2;     // 0..1  -> M offset wr*128
  const int wc = w & 3;      // 0..3  -> N offset wc*64

  // staging: thread tid, chunk i -> LDS row i*64 + (tid>>3), slot tid&7
  // linear; global source column pre-swizzled
  // k8 = (tid&7) ^ (row&7) ^ ((row>>3)&3), row = tid>>3 (invariant +64i).
  const int rb   = tid >> 3;
  const int slot = (tid & 7) ^ (rb & 7) ^ ((rb >> 3) & 3);
  const u16* gA_0 = A  + (size_t)(bm + rb) * K + slot * 8;
  const u16* gA_1 = gA_0 + (size_t)64  * K;
  const u16* gA_2 = gA_0 + (size_t)128 * K;
  const u16* gA_3 = gA_0 + (size_t)192 * K;
  const u16* gB_0 = Wm + (size_t)(bn + rb) * K + slot * 8;
  const u16* gB_1 = gB_0 + (size_t)64  * K;
  const u16* gB_2 = gB_0 + (size_t)128 * K;
  const u16* gB_3 = gB_0 + (size_t)192 * K;

  // fragment reads: row = base + (l&31);
  // k-step s slot = (2s + (l>>5)) ^ (l&7) ^ ((l>>3)&3)
  const int arow = wr * 128 + (l & 31);
  const int brow = wc * 64 + (l & 31);
  const int g  = l >> 5;
  const int xs = (l & 7) ^ ((l >> 3) & 3);
  const int sl0 = ((0 + g) ^ xs) * 8;  // s=0
  const int sl1 = ((2 + g) ^ xs) * 8;  // s=1
  const int sl2 = ((4 + g) ^ xs) * 8;  // s=2
  const int sl3 = ((6 + g) ^ xs) * 8;  // s=3

  f32x16 acc[4][2];
#pragma unroll
  for (int i = 0; i < 4; ++i)
#pragma unroll
    for (int j = 0; j < 2; ++j)
#pragma unroll
      for (int r = 0; r < 16; ++r) acc[i][j][r] = 0.f;

  // prologue: stage K-tile 0 into buffer 0 (8 loads in flight, no drain)
  STAGE_A(0, 0)
  STAGE_B(0, 0)

  for (int t = 0; t < NT; ++t) {
    const int cur = t & 1, nxt = cur ^ 1;
    const u16* sa = sA[cur];
    const u16* sb = sB[cur];

    // stage t+1 (safe: BAR_A(t-1) retired all reads of buf[nxt]);
    // VMW before BAR_B makes tile t's arrival collective.
    if (t < NT - 1) {
      const int kn = (t + 1) << 6;
      STAGE_A(nxt, kn)
      STAGE_B(nxt, kn)
      VMW(8)
    } else {
      VMW(0)
    }
    BAR  // BAR_B

    bf16x8 a0e, a1e, a2e, a3e, a0o, a1o, a2o, a3o, b0e, b1e, b0o, b1o;
    // k-steps 0,1: 12 ds_read_b128 + 16 MFMA (compiler emits counted lgkmcnt)
    RD12(sl0, sl1)
    MFMA8(a0e, a1e, a2e, a3e, b0e, b1e)
    MFMA8(a0o, a1o, a2o, a3o, b0o, b1o)
    // k-steps 2,3
    RD12(sl2, sl3)
    MFMA8(a0e, a1e, a2e, a3e, b0e, b1e)
    MFMA8(a0o, a1o, a2o, a3o, b0o, b1o)

    BAR  // BAR_A: all this wave's reads retired (lgkm before MFMA) for all
  }

  // C write (m74/m101 layout): col = lane&31,
  // row = (reg&3) + 8*(reg>>2) + 4*(lane>>5)
  const int ccol = bn + wc * 64 + (l & 31);
  const int crow = bm + wr * 128 + 4 * (l >> 5);
#pragma unroll
  for (int mi = 0; mi < 4; ++mi) {
#pragma unroll
    for (int nj = 0; nj < 2; ++nj) {
      int col = ccol + nj * 32;
#pragma unroll
      for (int r = 0; r < 16; ++r) {
        int row = crow + mi * 32 + (r & 3) + 8 * (r >> 2);
        C[(size_t)row * N + col] = f2bf(acc[mi][nj][r]);
      }
    }
  }
}

// ---------------- fused LN(ig) + LN(hg) + gates + cell-LN + outputs ----------
__global__ __launch_bounds__(256) void lstm_epilogue(
    const u16* __restrict__ ig, const u16* __restrict__ hg,
    const float* __restrict__ cx,
    const float* __restrict__ gi, const float* __restrict__ bi,
    const float* __restrict__ gh, const float* __restrict__ bh,
    const float* __restrict__ gc, const float* __restrict__ bc,
    float* __restrict__ out)
{
  const int b = blockIdx.x;
  const int t = threadIdx.x;
  const u16* igr = ig + (size_t)b * 4096;
  const u16* hgr = hg + (size_t)b * 4096;

  __shared__ float redbuf[16];

  float iv[16], hv[16];
  float s_i = 0.f, q_i = 0.f, s_h = 0.f, q_h = 0.f;
#pragma unroll
  for (int i = 0; i < 16; ++i) {
    float a = bf2f(igr[t + 256 * i]);
    float c = bf2f(hgr[t + 256 * i]);
    iv[i] = a; hv[i] = c;
    s_i += a; q_i += a * a; s_h += c; q_h += c * c;
  }
#pragma unroll
  for (int off = 32; off > 0; off >>= 1) {
    s_i += __shfl_xor(s_i, off);
    q_i += __shfl_xor(q_i, off);
    s_h += __shfl_xor(s_h, off);
    q_h += __shfl_xor(q_h, off);
  }
  {
    int wv = t >> 6;
    if ((t & 63) == 0) {
      redbuf[wv] = s_i; redbuf[wv + 4] = q_i;
      redbuf[wv + 8] = s_h; redbuf[wv + 12] = q_h;
    }
    __syncthreads();
    s_i = redbuf[0] + redbuf[1] + redbuf[2] + redbuf[3];
    q_i = redbuf[4] + redbuf[5] + redbuf[6] + redbuf[7];
    s_h = redbuf[8] + redbuf[9] + redbuf[10] + redbuf[11];
    q_h = redbuf[12] + redbuf[13] + redbuf[14] + redbuf[15];
    __syncthreads();
  }
  const float inv4096 = 1.0f / 4096.0f;
  float mu_i = s_i * inv4096;
  float rs_i = rsqrtf(q_i * inv4096 - mu_i * mu_i + EPS);
  float mu_h = s_h * inv4096;
  float rs_h = rsqrtf(q_h * inv4096 - mu_h * mu_h + EPS);

  float c_pre[4], og[4];
  float s_c = 0.f, q_c = 0.f;
#pragma unroll
  for (int i = 0; i < 4; ++i) {
    int h = t + 256 * i;
    float g_in = ((iv[i]      - mu_i) * rs_i * gi[h]        + bi[h]) +
                 ((hv[i]      - mu_h) * rs_h * gh[h]        + bh[h]);
    float g_fg = ((iv[i + 4]  - mu_i) * rs_i * gi[h + 1024] + bi[h + 1024]) +
                 ((hv[i + 4]  - mu_h) * rs_h * gh[h + 1024] + bh[h + 1024]);
    float g_cl = ((iv[i + 8]  - mu_i) * rs_i * gi[h + 2048] + bi[h + 2048]) +
                 ((hv[i + 8]  - mu_h) * rs_h * gh[h + 2048] + bh[h + 2048]);
    float g_og = ((iv[i + 12] - mu_i) * rs_i * gi[h + 3072] + bi[h + 3072]) +
                 ((hv[i + 12] - mu_h) * rs_h * gh[h + 3072] + bh[h + 3072]);
    float in_s = sigmoidf(g_in);
    float fg_s = sigmoidf(g_fg);
    float cl_t = tanhf(g_cl);
    og[i] = sigmoidf(g_og);
    c_pre[i] = fg_s * cx[(size_t)b * 1024 + h] + in_s * cl_t;
    s_c += c_pre[i]; q_c += c_pre[i] * c_pre[i];
  }
#pragma unroll
  for (int off = 32; off > 0; off >>= 1) {
    s_c += __shfl_xor(s_c, off);
    q_c += __shfl_xor(q_c, off);
  }
  {
    int wv = t >> 6;
    if ((t & 63) == 0) { redbuf[wv] = s_c; redbuf[wv + 4] = q_c; }
    __syncthreads();
    s_c = redbuf[0] + redbuf[1] + redbuf[2] + redbuf[3];
    q_c = redbuf[4] + redbuf[5] + redbuf[6] + redbuf[7];
  }
  const float inv1024 = 1.0f / 1024.0f;
  float mu_c = s_c * inv1024;
  float rs_c = rsqrtf(q_c * inv1024 - mu_c * mu_c + EPS);

  const size_t BH = (size_t)4096 * 1024;
#pragma unroll
  for (int i = 0; i < 4; ++i) {
    int h = t + 256 * i;
    float cy = (c_pre[i] - mu_c) * rs_c * gc[h] + bc[h];
    float hy = og[i] * tanhf(cy);
    size_t o = (size_t)b * 1024 + h;
    out[o] = hy;
    out[BH + o] = hy;
    out[2 * BH + o] = cy;
  }
}

extern "C" void kernel_launch(void* const* d_in, const int* in_sizes, int n_in,
                              void* d_out, int out_size, void* d_ws, size_t ws_size,
                              hipStream_t stream) {
  const float* input = (const float*)d_in[0];
  const float* hx    = (const float*)d_in[1];
  const float* cx    = (const float*)d_in[2];
  const float* wih   = (const float*)d_in[3];
  const float* whh   = (const float*)d_in[4];
  const float* gi    = (const float*)d_in[5];
  const float* bi    = (const float*)d_in[6];
  const float* gh    = (const float*)d_in[7];
  const float* bh    = (const float*)d_in[8];
  const float* gc    = (const float*)d_in[9];
  const float* bc    = (const float*)d_in[10];
  float* out = (float*)d_out;

  char* wsp = (char*)d_ws;
  u16* a_bf  = (u16*)(wsp);
  u16* h_bf  = (u16*)(wsp + ((size_t)8  << 20));
  u16* wi_bf = (u16*)(wsp + ((size_t)16 << 20));
  u16* wh_bf = (u16*)(wsp + ((size_t)24 << 20));
  u16* ig_bf = (u16*)(wsp + ((size_t)32 << 20));
  u16* hg_bf = (u16*)(wsp + ((size_t)64 << 20));

  const int nper = 4096 * 1024;
  dim3 cgrid(nper / 8 / 256, 4);
  cast4_f32_bf16<<<cgrid, 256, 0, stream>>>(input, hx, wih, whh,
                                            a_bf, h_bf, wi_bf, wh_bf, nper);

  gemm256_dual<<<512, 512, 0, stream>>>(a_bf, wi_bf, ig_bf,
                                        h_bf, wh_bf, hg_bf);

  lstm_epilogue<<<4096, 256, 0, stream>>>(ig_bf, hg_bf, cx,
                                          gi, bi, gh, bh, gc, bc, out);
}